// Round 15
// baseline (1300.358 us; speedup 1.0000x reference)
//
#include <hip/hip_runtime.h>

typedef __attribute__((ext_vector_type(4))) float f32x4;
typedef __attribute__((ext_vector_type(8))) short s16x8;
typedef __attribute__((ext_vector_type(4))) short s16x4;

__device__ __forceinline__ short f2bf(float f) {
  return __builtin_bit_cast(short, (__bf16)f);
}
__device__ __forceinline__ float bf2f(short s) {
  union { unsigned u; float f; } v; v.u = ((unsigned)(unsigned short)s) << 16;
  return v.f;
}
__device__ __forceinline__ f32x4 mfma16(s16x8 a, s16x8 b, f32x4 c) {
  return __builtin_amdgcn_mfma_f32_16x16x32_bf16(a, b, c, 0, 0, 0);
}

#define AS1(p) ((__attribute__((address_space(1))) void*)(p))
#define AS3(p) ((__attribute__((address_space(3))) void*)(p))

// ---------------- fp32 -> bf16 convert ----------------
__global__ __launch_bounds__(256) void cvt_bf16_kernel(const float* __restrict__ in,
                                                       short* __restrict__ out, long n) {
  long i = ((long)blockIdx.x * 256 + threadIdx.x) * 4;
  if (i + 4 <= n) {
    f32x4 v = *(const f32x4*)(in + i);
    s16x4 o;
    o[0] = f2bf(v[0]); o[1] = f2bf(v[1]); o[2] = f2bf(v[2]); o[3] = f2bf(v[3]);
    *(s16x4*)(out + i) = o;
  }
}

// ---------------- concat 3 bias vectors ----------------
__global__ __launch_bounds__(256) void bias_cat_kernel(const float* __restrict__ bq,
                                                       const float* __restrict__ bk,
                                                       const float* __restrict__ bv,
                                                       float* __restrict__ o) {
  int i = blockIdx.x * 256 + threadIdx.x;
  if (i < 3072) o[i] = (i < 1024) ? bq[i] : ((i < 2048) ? bk[i - 1024] : bv[i - 2048]);
}

// ---------------- rel table prep ----------------
__global__ __launch_bounds__(64) void prep_rel_kernel(
    const float* __restrict__ rq, const float* __restrict__ rk, const float* __restrict__ rv,
    short* __restrict__ relqb, short* __restrict__ relkb, short* __restrict__ relvT,
    float* __restrict__ Dh) {
  int h = blockIdx.x / 240;
  int r = blockIdx.x % 240;
  int d = threadIdx.x;
  float vq = 0.f, vk = 0.f, vv = 0.f;
  if (r < 225) {
    long o = ((long)h * 225 + r) * 64 + d;
    vq = rq[o]; vk = rk[o]; vv = rv[o];
  }
  relqb[((long)h * 240 + r) * 64 + d] = f2bf(vq);
  relkb[((long)h * 240 + r) * 64 + d] = f2bf(vk);
  relvT[((long)h * 64 + d) * 256 + r] = f2bf(vv);
  if (r < 16) relvT[((long)h * 64 + d) * 256 + 240 + r] = 0;
  float p = vq * vk;
  #pragma unroll
  for (int m = 32; m >= 1; m >>= 1) p += __shfl_xor(p, m);
  if (d == 0) Dh[h * 240 + r] = p;
}

// ============ 256x256 8-phase GEMM: C = A(M x K, lda) @ Bw(N x K)^T + bias ============
#define BAR  __builtin_amdgcn_s_barrier()
#define LGK0 do { asm volatile("s_waitcnt lgkmcnt(0)" ::: "memory"); \
                  __builtin_amdgcn_sched_barrier(0); } while (0)
#define VM0  asm volatile("s_waitcnt vmcnt(0)" ::: "memory")
#define PRIO1 __builtin_amdgcn_s_setprio(1)
#define PRIO0 __builtin_amdgcn_s_setprio(0)

#define STG_A(D, H, KOFF) do { \
    const short* _s = gA + (long)(H) * 128 * ldaL + (KOFF); \
    char* _d = lds + (D) * 32768 + (H) * 16384 + ldsw; \
    __builtin_amdgcn_global_load_lds(AS1(_s), AS3(_d), 16, 0, 0); \
    __builtin_amdgcn_global_load_lds(AS1(_s + 64 * ldaL), AS3(_d + 8192), 16, 0, 0); \
  } while (0)
#define STG_B(D, H, KOFF) do { \
    const short* _s = gB + (long)(H) * 128 * ldbL + (KOFF); \
    char* _d = lds + 65536 + (D) * 32768 + (H) * 16384 + ldsw; \
    __builtin_amdgcn_global_load_lds(AS1(_s), AS3(_d), 16, 0, 0); \
    __builtin_amdgcn_global_load_lds(AS1(_s + 64 * ldbL), AS3(_d + 8192), 16, 0, 0); \
  } while (0)
#define RD_A(D, MIH) do { \
    const char* _b = lds + (D) * 32768 + baseA + (MIH) * 8192; \
    _Pragma("unroll") for (int i = 0; i < 4; i++) { \
      aa[0][i] = *(const s16x8*)(_b + i * 2048 + cax0); \
      aa[1][i] = *(const s16x8*)(_b + i * 2048 + cax1); \
    } } while (0)
#define RD_B(D, NJH) do { \
    const char* _b = lds + (D) * 32768 + baseB + (NJH) * 4096; \
    _Pragma("unroll") for (int j = 0; j < 2; j++) { \
      bb[0][(NJH) * 2 + j] = *(const s16x8*)(_b + j * 2048 + cax0); \
      bb[1][(NJH) * 2 + j] = *(const s16x8*)(_b + j * 2048 + cax1); \
    } } while (0)
#define MM_Q(MIH, NJH) do { \
    _Pragma("unroll") for (int i = 0; i < 4; i++) { \
      _Pragma("unroll") for (int j = 0; j < 2; j++) { \
        f32x4& c = acc[(MIH) * 4 + i][(NJH) * 2 + j]; \
        c = mfma16(bb[0][(NJH) * 2 + j], aa[0][i], c); \
        c = mfma16(bb[1][(NJH) * 2 + j], aa[1][i], c); \
    } } } while (0)

template<int OUT_BF16>
__global__ __launch_bounds__(512, 2) void gemm256_kernel(
    const short* __restrict__ A, const short* __restrict__ Bw,
    const float* __restrict__ bias, void* __restrict__ Cout,
    int N, int K, int lda) {
  __shared__ __attribute__((aligned(16))) char lds[131072];
  const int tid = threadIdx.x, lane = tid & 63, w = tid >> 6;
  const int wr = w >> 2, wc = w & 3;
  const int l15 = lane & 15, l4 = lane >> 4;
  const int nbn = N >> 8;
  const int nwg = gridDim.x, bid = blockIdx.x;
  const int swz = ((bid & 7) * (nwg >> 3)) + (bid >> 3);   // XCD swizzle (nwg%8==0)
  const int bm = swz / nbn, bn = swz % nbn;

  const int srow = tid >> 3;
  const int scol = ((tid & 7) ^ (srow & 7)) * 8;           // pre-swizzled source chunk
  const long ldaL = lda, ldbL = K;
  const short* gA = A  + ((long)(bm * 256 + srow)) * ldaL + scol;
  const short* gB = Bw + ((long)(bn * 256 + srow)) * ldbL + scol;
  const int ldsw = w * 1024;

  const int baseA = (wr * 128 + l15) * 128;
  const int baseB = 65536 + (wc * 64 + l15) * 128;
  const int cax0 = ((l4) ^ (l15 & 7)) * 16;
  const int cax1 = ((4 + l4) ^ (l15 & 7)) * 16;

  f32x4 acc[8][4];
  #pragma unroll
  for (int i = 0; i < 8; i++)
    #pragma unroll
    for (int j = 0; j < 4; j++) acc[i][j] = (f32x4){0.f, 0.f, 0.f, 0.f};
  s16x8 aa[2][4], bb[2][4];

  STG_A(0, 0, 0); STG_A(0, 1, 0); STG_B(0, 0, 0); STG_B(0, 1, 0);
  STG_B(1, 0, 64); STG_B(1, 1, 64);
  VM0;
  BAR;

  const int NT = K >> 6;
  for (int kt = 0; kt < NT; kt += 2) {
    const int k1 = (kt + 1) << 6, k2 = (kt + 2) << 6, k3 = (kt + 3) << 6;
    const bool full = (kt + 2) < NT;
    STG_A(1, 0, k1);
    RD_A(0, 0); RD_B(0, 0);
    BAR; LGK0; PRIO1; MM_Q(0, 0); PRIO0; BAR;
    STG_A(1, 1, k1);
    RD_B(0, 1);
    BAR; LGK0; PRIO1; MM_Q(0, 1); PRIO0; BAR;
    if (full) STG_B(0, 0, k2);
    RD_A(0, 1);
    BAR; LGK0; PRIO1; MM_Q(1, 0); PRIO0; BAR;
    if (full) STG_B(0, 1, k2);
    BAR; LGK0; PRIO1; MM_Q(1, 1); PRIO0;
    VM0;
    BAR;
    if (full) STG_A(0, 0, k2);
    RD_A(1, 0); RD_B(1, 0);
    BAR; LGK0; PRIO1; MM_Q(0, 0); PRIO0; BAR;
    if (full) STG_A(0, 1, k2);
    RD_B(1, 1);
    BAR; LGK0; PRIO1; MM_Q(0, 1); PRIO0; BAR;
    if (full) STG_B(1, 0, k3);
    RD_A(1, 1);
    BAR; LGK0; PRIO1; MM_Q(1, 0); PRIO0; BAR;
    if (full) STG_B(1, 1, k3);
    BAR; LGK0; PRIO1; MM_Q(1, 1); PRIO0;
    VM0;
    BAR;
  }

  const long crow = (long)bm * 256 + wr * 128;
  const int ccol = bn * 256 + wc * 64;
  #pragma unroll
  for (int nj = 0; nj < 4; nj++) {
    const int colb = ccol + nj * 16 + l4 * 4;
    const f32x4 bv4 = *(const f32x4*)&bias[colb];
    #pragma unroll
    for (int mi = 0; mi < 8; mi++) {
      const long row = crow + mi * 16 + l15;
      f32x4 v = acc[mi][nj] + bv4;
      if (OUT_BF16) {
        s16x4 o;
        o[0] = f2bf(v[0]); o[1] = f2bf(v[1]); o[2] = f2bf(v[2]); o[3] = f2bf(v[3]);
        *(s16x4*)((short*)Cout + row * N + colb) = o;
      } else {
        *(f32x4*)((float*)Cout + row * N + colb) = v;
      }
    }
  }
}

// ---------------- fused relative attention v5 ----------------
// v4 + (1) conflict-free vts staging: lane's d-set {(l&3)*2+e+8p} gives 4 distinct
// swizzle nibbles per store instruction -> bank sets 0/8/16/24 (was 8-way on one set);
// (2) Pb row stride 640 -> 656 (bank +4 per t-row, de-aliases scatter + PV reads);
// (3) exp2-domain softmax (scale folds log2(e); exp2f instead of __expf).
#define PBS 656
__global__ __launch_bounds__(512, 4) void attn_kernel(
    const short* __restrict__ qkv, const short* __restrict__ relqb,
    const short* __restrict__ relkb, const float* __restrict__ Dh,
    const short* __restrict__ relvT, short* __restrict__ aout) {
  __shared__ __attribute__((aligned(16))) char region[65536];
  __shared__ __attribute__((aligned(16))) char vts[8192];

  const int tid = threadIdx.x, lane = tid & 63, w = tid >> 6;
  const int l15 = lane & 15, l4 = lane >> 4;
  const int bh = blockIdx.x, b = bh >> 4, h = bh & 15;
  const f32x4 zero = {0.f, 0.f, 0.f, 0.f};

  char* qrs = region;            // qr [64 t][512B], swizzled
  char* krs = region + 32768;    // kr [64 s][512B], swizzled

  f32x4 sacc[4];
  float att[4][4];

  if (w < 4) {
    // q fragments for all 4 t-tiles (A-op for S tile w; B-op for qr)
    s16x8 aqs[4][2];
    #pragma unroll
    for (int tb = 0; tb < 4; tb++) {
      const long qb = ((long)(b * 64 + tb * 16 + l15)) * 3072 + h * 64;
      aqs[tb][0] = *(const s16x8*)(qkv + qb + l4 * 8);
      aqs[tb][1] = *(const s16x8*)(qkv + qb + 32 + l4 * 8);
    }
    // S = q @ k^T (row-tile w)
    sacc[0] = sacc[1] = sacc[2] = sacc[3] = zero;
    #pragma unroll
    for (int n = 0; n < 4; n++) {
      const long kb = ((long)(b * 64 + n * 16 + l15)) * 3072 + 1024 + h * 64;
      s16x8 b0 = *(const s16x8*)(qkv + kb + l4 * 8);
      s16x8 b1 = *(const s16x8*)(qkv + kb + 32 + l4 * 8);
      sacc[n] = mfma16(aqs[w][0], b0, sacc[n]);
      sacc[n] = mfma16(aqs[w][1], b1, sacc[n]);
    }
    // qr (+Dh) for own nj set over all t
    const short* rkh = relkb + (long)h * 240 * 64;
    #pragma unroll
    for (int g = 0; g < 4; g++) {
      const int nj = w + g * 4;
      if (nj < 15) {
        const int rr = nj * 16 + l15;
        s16x8 r0 = *(const s16x8*)(rkh + rr * 64 + l4 * 8);
        s16x8 r1 = *(const s16x8*)(rkh + rr * 64 + 32 + l4 * 8);
        const f32x4 dv4 = *(const f32x4*)&Dh[h * 240 + nj * 16 + l4 * 4];
        #pragma unroll
        for (int tb = 0; tb < 4; tb++) {
          f32x4 t0 = mfma16(r1, aqs[tb][1], mfma16(r0, aqs[tb][0], zero));
          const int t = tb * 16 + l15;
          s16x4 q4;
          #pragma unroll
          for (int j = 0; j < 4; j++) q4[j] = f2bf(t0[j] + dv4[j]);
          *(s16x4*)(qrs + t * 512 + ((nj * 32 + l4 * 8) ^ ((t & 7) << 4))) = q4;
        }
      }
    }
  } else {
    // conflict-free v^T staging: lane (wl, l) owns t = wl*16 + (l>>2) and
    // d-set {(l&3)*2 + e + 8p}; per store instruction the 4 quarter-groups carry
    // 4 distinct swizzle nibbles -> disjoint bank sets.
    const int wl = w - 4;
    const int tv = wl * 16 + (lane >> 2);
    const int q2 = (lane & 3) * 2;
    const short* gv = qkv + ((long)(b * 64 + tv)) * 3072 + 2048 + h * 64 + q2;
    const int tterm = tv * 2;
    #pragma unroll
    for (int p = 0; p < 8; p++) {
      const unsigned vv = *(const unsigned*)(gv + p * 8);
      const int d0 = q2 + p * 8;
      const int d1 = d0 + 1;
      *(short*)(vts + d0 * 128 + (tterm ^ ((d0 & 7) << 4))) = (short)vv;
      *(short*)(vts + d1 * 128 + (tterm ^ ((d1 & 7) << 4))) = (short)(vv >> 16);
    }
    // k fragments for all 4 s-tiles
    s16x8 aks[4][2];
    #pragma unroll
    for (int sb = 0; sb < 4; sb++) {
      const long kb = ((long)(b * 64 + sb * 16 + l15)) * 3072 + 1024 + h * 64;
      aks[sb][0] = *(const s16x8*)(qkv + kb + l4 * 8);
      aks[sb][1] = *(const s16x8*)(qkv + kb + 32 + l4 * 8);
    }
    // kr for own nj set over all s
    const short* rqh = relqb + (long)h * 240 * 64;
    #pragma unroll
    for (int g4 = 0; g4 < 4; g4++) {
      const int nj = wl + g4 * 4;
      if (nj < 15) {
        const int rr = nj * 16 + l15;
        s16x8 r0 = *(const s16x8*)(rqh + rr * 64 + l4 * 8);
        s16x8 r1 = *(const s16x8*)(rqh + rr * 64 + 32 + l4 * 8);
        #pragma unroll
        for (int sb = 0; sb < 4; sb++) {
          f32x4 t1 = mfma16(r1, aks[sb][1], mfma16(r0, aks[sb][0], zero));
          const int s = sb * 16 + l15;
          s16x4 k4;
          #pragma unroll
          for (int j = 0; j < 4; j++) k4[j] = f2bf(t1[j]);
          *(s16x4*)(krs + s * 512 + ((nj * 32 + l4 * 8) ^ ((s & 7) << 4))) = k4;
        }
      }
    }
  }
  __syncthreads();   // barrier 1: qr/kr/vts visible

  // ---- PV operand prefetch (ALL waves): 16 relvT fragments into regs ----
  const int tc = w & 3, mb = (w >> 2) * 2;
  const short* rvh = relvT + (long)h * 16384;
  s16x8 rv0[8], rv1[8];
  #pragma unroll
  for (int kk = 0; kk < 8; kk++) {
    rv0[kk] = *(const s16x8*)(rvh + ((mb + 0) * 16 + l15) * 256 + kk * 32 + l4 * 8);
    rv1[kk] = *(const s16x8*)(rvh + ((mb + 1) * 16 + l15) * 256 + kk * 32 + l4 * 8);
  }

  if (w < 4) {
    // gather + logits (exp2 domain) + softmax
    const float scale2 = 0.18033688f;   // 0.125 * log2(e)
    const int tx0 = (l4 & 1) * 4;
    const int ty = w * 2 + (l4 >> 1);
    const int tbase = w * 16 + l4 * 4;
    #pragma unroll
    for (int n = 0; n < 4; n++) {
      const int s = n * 16 + l15;
      const int sx = s & 7, sy = s >> 3;
      const int r0 = (7 - tx0 + sx) + 15 * (7 - ty + sy);
      const int kga = s * 512;
      const int ksw = (s & 7) << 4;
      #pragma unroll
      for (int j = 0; j < 4; j++) {
        const int t = tbase + j;
        const int r = r0 - j;
        const float qg = bf2f(*(const short*)(qrs + t * 512 + ((r * 2) ^ ((t & 7) << 4))));
        const float kg = bf2f(*(const short*)(krs + kga + ((r * 2) ^ ksw)));
        sacc[n][j] = (sacc[n][j] + qg + kg) * scale2;
      }
    }
    #pragma unroll
    for (int j = 0; j < 4; j++) {
      float m = fmaxf(fmaxf(sacc[0][j], sacc[1][j]), fmaxf(sacc[2][j], sacc[3][j]));
      m = fmaxf(m, __shfl_xor(m, 1));
      m = fmaxf(m, __shfl_xor(m, 2));
      m = fmaxf(m, __shfl_xor(m, 4));
      m = fmaxf(m, __shfl_xor(m, 8));
      float sum = 0.f;
      #pragma unroll
      for (int n = 0; n < 4; n++) { att[n][j] = exp2f(sacc[n][j] - m); sum += att[n][j]; }
      sum += __shfl_xor(sum, 1);
      sum += __shfl_xor(sum, 2);
      sum += __shfl_xor(sum, 4);
      sum += __shfl_xor(sum, 8);
      const float inv = 1.f / sum;
      #pragma unroll
      for (int n = 0; n < 4; n++) att[n][j] *= inv;
    }
  }
  __syncthreads();   // barrier 2: qr/kr reads done -> region reusable as Pb

  char* Pb = region;
  if (w < 4) {
    // zero wave-own P rows (512B P-part; attn part fully overwritten below)
    s16x8 z = {0, 0, 0, 0, 0, 0, 0, 0};
    #pragma unroll
    for (int i = 0; i < 8; i++) {
      const int c = lane + 64 * i;
      *(s16x8*)(Pb + (w * 16 + (c >> 5)) * PBS + (c & 31) * 16) = z;
    }
    const int tx0 = (l4 & 1) * 4;
    const int ty = w * 2 + (l4 >> 1);
    const int tbase = w * 16 + l4 * 4;
    #pragma unroll
    for (int n = 0; n < 4; n++) {
      const int s = n * 16 + l15;
      const int sx = s & 7, sy = s >> 3;
      const int r0 = (7 - tx0 + sx) + 15 * (7 - ty + sy);
      #pragma unroll
      for (int j = 0; j < 4; j++) {
        const int t = tbase + j;
        const int r = r0 - j;
        const int sw = (t & 7) << 4;
        const short a = f2bf(att[n][j]);
        *(short*)(Pb + t * PBS + ((r * 2) ^ sw)) = a;
        *(short*)(Pb + t * PBS + 512 + ((s * 2) ^ sw)) = a;
      }
    }
  }
  __syncthreads();   // barrier 3: Pb complete

  // PV: wave w owns t-column tc and d-blocks mb, mb+1 (relvT operands in regs)
  const int rowp = tc * 16 + l15, px = (rowp & 7) << 4;
  f32x4 oacc0 = zero, oacc1 = zero;
  PRIO1;
  #pragma unroll
  for (int kk = 0; kk < 8; kk++) {
    s16x8 pa = *(const s16x8*)(Pb + rowp * PBS + ((kk * 64 + l4 * 16) ^ px));
    oacc0 = mfma16(rv0[kk], pa, oacc0);
    oacc1 = mfma16(rv1[kk], pa, oacc1);
  }
  #pragma unroll
  for (int ks = 0; ks < 2; ks++) {
    s16x8 pa = *(const s16x8*)(Pb + rowp * PBS + 512 + ((ks * 64 + l4 * 16) ^ px));
    const int d0 = (mb + 0) * 16 + l15;
    const int d1 = (mb + 1) * 16 + l15;
    s16x8 bv0 = *(const s16x8*)(vts + d0 * 128 + ((ks * 64 + l4 * 16) ^ ((d0 & 7) << 4)));
    s16x8 bv1 = *(const s16x8*)(vts + d1 * 128 + ((ks * 64 + l4 * 16) ^ ((d1 & 7) << 4)));
    oacc0 = mfma16(bv0, pa, oacc0);
    oacc1 = mfma16(bv1, pa, oacc1);
  }
  PRIO0;
  // out[d][t]: packed 8-B stores
  const long obase = ((long)(b * 64 + rowp)) * 1024 + h * 64 + l4 * 4;
  {
    s16x4 o0, o1;
    #pragma unroll
    for (int j = 0; j < 4; j++) { o0[j] = f2bf(oacc0[j]); o1[j] = f2bf(oacc1[j]); }
    *(s16x4*)(aout + obase + (mb + 0) * 16) = o0;
    *(s16x4*)(aout + obase + (mb + 1) * 16) = o1;
  }
}

extern "C" void kernel_launch(void* const* d_in, const int* in_sizes, int n_in,
                              void* d_out, int out_size, void* d_ws, size_t ws_size,
                              hipStream_t stream) {
  const float* x     = (const float*)d_in[0];
  const float* Wq_w  = (const float*)d_in[1];
  const float* Wq_b  = (const float*)d_in[2];
  const float* Wk_w  = (const float*)d_in[3];
  const float* Wk_b  = (const float*)d_in[4];
  const float* Wv_w  = (const float*)d_in[5];
  const float* Wv_b  = (const float*)d_in[6];
  const float* Wo_w  = (const float*)d_in[7];
  const float* Wo_b  = (const float*)d_in[8];
  const float* rel_q = (const float*)d_in[9];
  const float* rel_k = (const float*)d_in[10];
  const float* rel_v = (const float*)d_in[11];
  float* out = (float*)d_out;

  char* ws = (char*)d_ws;
  short* x_bf   = (short*)(ws);                   // 134,217,728 (reused as aout)
  short* qkv_bf = (short*)(ws + 134217728L);      // 402,653,184
  short* wq_bf  = (short*)(ws + 536870912L);      // wq|wk|wv contiguous
  short* wo_bf  = (short*)(ws + 543162368L);
  float* biascat= (float*)(ws + 545259520L);
  short* relqb  = (short*)(ws + 545271808L);
  short* relkb  = (short*)(ws + 545763328L);
  short* relvT  = (short*)(ws + 546254848L);
  float* Dh     = (float*)(ws + 546779136L);
  short* aout   = x_bf;

  cvt_bf16_kernel<<<65536, 256, 0, stream>>>(x, x_bf, 67108864L);
  cvt_bf16_kernel<<<1024, 256, 0, stream>>>(Wq_w, wq_bf, 1048576L);
  cvt_bf16_kernel<<<1024, 256, 0, stream>>>(Wk_w, (short*)(ws + 538968064L), 1048576L);
  cvt_bf16_kernel<<<1024, 256, 0, stream>>>(Wv_w, (short*)(ws + 541065216L), 1048576L);
  cvt_bf16_kernel<<<1024, 256, 0, stream>>>(Wo_w, wo_bf, 1048576L);
  bias_cat_kernel<<<12, 256, 0, stream>>>(Wq_b, Wk_b, Wv_b, biascat);
  prep_rel_kernel<<<3840, 64, 0, stream>>>(rel_q, rel_k, rel_v, relqb, relkb, relvT, Dh);

  gemm256_kernel<1><<<3072, 512, 0, stream>>>(x_bf, wq_bf, biascat, (void*)qkv_bf,
                                              3072, 1024, 1024);
  attn_kernel<<<16384, 512, 0, stream>>>(qkv_bf, relqb, relkb, Dh, relvT, aout);
  gemm256_kernel<0><<<1024, 512, 0, stream>>>(aout, wo_bf, Wo_b, (void*)out,
                                              1024, 1024, 1024);
}

// Round 16
// 1289.955 us; speedup vs baseline: 1.0081x; 1.0081x over previous
//
#include <hip/hip_runtime.h>

typedef __attribute__((ext_vector_type(4))) float f32x4;
typedef __attribute__((ext_vector_type(8))) short s16x8;
typedef __attribute__((ext_vector_type(4))) short s16x4;

__device__ __forceinline__ short f2bf(float f) {
  return __builtin_bit_cast(short, (__bf16)f);
}
__device__ __forceinline__ float bf2f(short s) {
  union { unsigned u; float f; } v; v.u = ((unsigned)(unsigned short)s) << 16;
  return v.f;
}
__device__ __forceinline__ f32x4 mfma16(s16x8 a, s16x8 b, f32x4 c) {
  return __builtin_amdgcn_mfma_f32_16x16x32_bf16(a, b, c, 0, 0, 0);
}

#define AS1(p) ((__attribute__((address_space(1))) void*)(p))
#define AS3(p) ((__attribute__((address_space(3))) void*)(p))

// ---------------- fp32 -> bf16 convert ----------------
__global__ __launch_bounds__(256) void cvt_bf16_kernel(const float* __restrict__ in,
                                                       short* __restrict__ out, long n) {
  long i = ((long)blockIdx.x * 256 + threadIdx.x) * 4;
  if (i + 4 <= n) {
    f32x4 v = *(const f32x4*)(in + i);
    s16x4 o;
    o[0] = f2bf(v[0]); o[1] = f2bf(v[1]); o[2] = f2bf(v[2]); o[3] = f2bf(v[3]);
    *(s16x4*)(out + i) = o;
  }
}

// ---------------- concat 3 bias vectors ----------------
__global__ __launch_bounds__(256) void bias_cat_kernel(const float* __restrict__ bq,
                                                       const float* __restrict__ bk,
                                                       const float* __restrict__ bv,
                                                       float* __restrict__ o) {
  int i = blockIdx.x * 256 + threadIdx.x;
  if (i < 3072) o[i] = (i < 1024) ? bq[i] : ((i < 2048) ? bk[i - 1024] : bv[i - 2048]);
}

// ---------------- rel table prep ----------------
__global__ __launch_bounds__(64) void prep_rel_kernel(
    const float* __restrict__ rq, const float* __restrict__ rk, const float* __restrict__ rv,
    short* __restrict__ relqb, short* __restrict__ relkb, short* __restrict__ relvT,
    float* __restrict__ Dh) {
  int h = blockIdx.x / 240;
  int r = blockIdx.x % 240;
  int d = threadIdx.x;
  float vq = 0.f, vk = 0.f, vv = 0.f;
  if (r < 225) {
    long o = ((long)h * 225 + r) * 64 + d;
    vq = rq[o]; vk = rk[o]; vv = rv[o];
  }
  relqb[((long)h * 240 + r) * 64 + d] = f2bf(vq);
  relkb[((long)h * 240 + r) * 64 + d] = f2bf(vk);
  relvT[((long)h * 64 + d) * 256 + r] = f2bf(vv);
  if (r < 16) relvT[((long)h * 64 + d) * 256 + 240 + r] = 0;
  float p = vq * vk;
  #pragma unroll
  for (int m = 32; m >= 1; m >>= 1) p += __shfl_xor(p, m);
  if (d == 0) Dh[h * 240 + r] = p;
}

// ============ 256x256 8-phase GEMM: C = A(M x K, lda) @ Bw(N x K)^T + bias ============
#define BAR  __builtin_amdgcn_s_barrier()
#define LGK0 do { asm volatile("s_waitcnt lgkmcnt(0)" ::: "memory"); \
                  __builtin_amdgcn_sched_barrier(0); } while (0)
#define VM0  asm volatile("s_waitcnt vmcnt(0)" ::: "memory")
#define PRIO1 __builtin_amdgcn_s_setprio(1)
#define PRIO0 __builtin_amdgcn_s_setprio(0)

#define STG_A(D, H, KOFF) do { \
    const short* _s = gA + (long)(H) * 128 * ldaL + (KOFF); \
    char* _d = lds + (D) * 32768 + (H) * 16384 + ldsw; \
    __builtin_amdgcn_global_load_lds(AS1(_s), AS3(_d), 16, 0, 0); \
    __builtin_amdgcn_global_load_lds(AS1(_s + 64 * ldaL), AS3(_d + 8192), 16, 0, 0); \
  } while (0)
#define STG_B(D, H, KOFF) do { \
    const short* _s = gB + (long)(H) * 128 * ldbL + (KOFF); \
    char* _d = lds + 65536 + (D) * 32768 + (H) * 16384 + ldsw; \
    __builtin_amdgcn_global_load_lds(AS1(_s), AS3(_d), 16, 0, 0); \
    __builtin_amdgcn_global_load_lds(AS1(_s + 64 * ldbL), AS3(_d + 8192), 16, 0, 0); \
  } while (0)
#define RD_A(D, MIH) do { \
    const char* _b = lds + (D) * 32768 + baseA + (MIH) * 8192; \
    _Pragma("unroll") for (int i = 0; i < 4; i++) { \
      aa[0][i] = *(const s16x8*)(_b + i * 2048 + cax0); \
      aa[1][i] = *(const s16x8*)(_b + i * 2048 + cax1); \
    } } while (0)
#define RD_B(D, NJH) do { \
    const char* _b = lds + (D) * 32768 + baseB + (NJH) * 4096; \
    _Pragma("unroll") for (int j = 0; j < 2; j++) { \
      bb[0][(NJH) * 2 + j] = *(const s16x8*)(_b + j * 2048 + cax0); \
      bb[1][(NJH) * 2 + j] = *(const s16x8*)(_b + j * 2048 + cax1); \
    } } while (0)
#define MM_Q(MIH, NJH) do { \
    _Pragma("unroll") for (int i = 0; i < 4; i++) { \
      _Pragma("unroll") for (int j = 0; j < 2; j++) { \
        f32x4& c = acc[(MIH) * 4 + i][(NJH) * 2 + j]; \
        c = mfma16(bb[0][(NJH) * 2 + j], aa[0][i], c); \
        c = mfma16(bb[1][(NJH) * 2 + j], aa[1][i], c); \
    } } } while (0)

template<int OUT_BF16>
__global__ __launch_bounds__(512, 2) void gemm256_kernel(
    const short* __restrict__ A, const short* __restrict__ Bw,
    const float* __restrict__ bias, void* __restrict__ Cout,
    int N, int K, int lda) {
  __shared__ __attribute__((aligned(16))) char lds[131072];
  const int tid = threadIdx.x, lane = tid & 63, w = tid >> 6;
  const int wr = w >> 2, wc = w & 3;
  const int l15 = lane & 15, l4 = lane >> 4;
  const int nbn = N >> 8;
  const int nwg = gridDim.x, bid = blockIdx.x;
  const int swz = ((bid & 7) * (nwg >> 3)) + (bid >> 3);   // XCD swizzle (nwg%8==0)
  const int bm = swz / nbn, bn = swz % nbn;

  const int srow = tid >> 3;
  const int scol = ((tid & 7) ^ (srow & 7)) * 8;           // pre-swizzled source chunk
  const long ldaL = lda, ldbL = K;
  const short* gA = A  + ((long)(bm * 256 + srow)) * ldaL + scol;
  const short* gB = Bw + ((long)(bn * 256 + srow)) * ldbL + scol;
  const int ldsw = w * 1024;

  const int baseA = (wr * 128 + l15) * 128;
  const int baseB = 65536 + (wc * 64 + l15) * 128;
  const int cax0 = ((l4) ^ (l15 & 7)) * 16;
  const int cax1 = ((4 + l4) ^ (l15 & 7)) * 16;

  f32x4 acc[8][4];
  #pragma unroll
  for (int i = 0; i < 8; i++)
    #pragma unroll
    for (int j = 0; j < 4; j++) acc[i][j] = (f32x4){0.f, 0.f, 0.f, 0.f};
  s16x8 aa[2][4], bb[2][4];

  STG_A(0, 0, 0); STG_A(0, 1, 0); STG_B(0, 0, 0); STG_B(0, 1, 0);
  STG_B(1, 0, 64); STG_B(1, 1, 64);
  VM0;
  BAR;

  const int NT = K >> 6;
  for (int kt = 0; kt < NT; kt += 2) {
    const int k1 = (kt + 1) << 6, k2 = (kt + 2) << 6, k3 = (kt + 3) << 6;
    const bool full = (kt + 2) < NT;
    STG_A(1, 0, k1);
    RD_A(0, 0); RD_B(0, 0);
    BAR; LGK0; PRIO1; MM_Q(0, 0); PRIO0; BAR;
    STG_A(1, 1, k1);
    RD_B(0, 1);
    BAR; LGK0; PRIO1; MM_Q(0, 1); PRIO0; BAR;
    if (full) STG_B(0, 0, k2);
    RD_A(0, 1);
    BAR; LGK0; PRIO1; MM_Q(1, 0); PRIO0; BAR;
    if (full) STG_B(0, 1, k2);
    BAR; LGK0; PRIO1; MM_Q(1, 1); PRIO0;
    VM0;
    BAR;
    if (full) STG_A(0, 0, k2);
    RD_A(1, 0); RD_B(1, 0);
    BAR; LGK0; PRIO1; MM_Q(0, 0); PRIO0; BAR;
    if (full) STG_A(0, 1, k2);
    RD_B(1, 1);
    BAR; LGK0; PRIO1; MM_Q(0, 1); PRIO0; BAR;
    if (full) STG_B(1, 0, k3);
    RD_A(1, 1);
    BAR; LGK0; PRIO1; MM_Q(1, 0); PRIO0; BAR;
    if (full) STG_B(1, 1, k3);
    BAR; LGK0; PRIO1; MM_Q(1, 1); PRIO0;
    VM0;
    BAR;
  }

  const long crow = (long)bm * 256 + wr * 128;
  const int ccol = bn * 256 + wc * 64;
  #pragma unroll
  for (int nj = 0; nj < 4; nj++) {
    const int colb = ccol + nj * 16 + l4 * 4;
    const f32x4 bv4 = *(const f32x4*)&bias[colb];
    #pragma unroll
    for (int mi = 0; mi < 8; mi++) {
      const long row = crow + mi * 16 + l15;
      f32x4 v = acc[mi][nj] + bv4;
      if (OUT_BF16) {
        s16x4 o;
        o[0] = f2bf(v[0]); o[1] = f2bf(v[1]); o[2] = f2bf(v[2]); o[3] = f2bf(v[3]);
        *(s16x4*)((short*)Cout + row * N + colb) = o;
      } else {
        *(f32x4*)((float*)Cout + row * N + colb) = v;
      }
    }
  }
}

// ---------------- fused relative attention (R14 config + exp2 softmax) ----------------
__global__ __launch_bounds__(512, 4) void attn_kernel(
    const short* __restrict__ qkv, const short* __restrict__ relqb,
    const short* __restrict__ relkb, const float* __restrict__ Dh,
    const short* __restrict__ relvT, short* __restrict__ aout) {
  __shared__ __attribute__((aligned(16))) char region[65536];
  __shared__ __attribute__((aligned(16))) char vts[8192];

  const int tid = threadIdx.x, lane = tid & 63, w = tid >> 6;
  const int l15 = lane & 15, l4 = lane >> 4;
  const int bh = blockIdx.x, b = bh >> 4, h = bh & 15;
  const f32x4 zero = {0.f, 0.f, 0.f, 0.f};

  char* qrs = region;            // qr [64 t][512B], swizzled
  char* krs = region + 32768;    // kr [64 s][512B], swizzled

  f32x4 sacc[4];
  float att[4][4];

  if (w < 4) {
    // q fragments for all 4 t-tiles (A-op for S tile w; B-op for qr)
    s16x8 aqs[4][2];
    #pragma unroll
    for (int tb = 0; tb < 4; tb++) {
      const long qb = ((long)(b * 64 + tb * 16 + l15)) * 3072 + h * 64;
      aqs[tb][0] = *(const s16x8*)(qkv + qb + l4 * 8);
      aqs[tb][1] = *(const s16x8*)(qkv + qb + 32 + l4 * 8);
    }
    // S = q @ k^T (row-tile w)
    sacc[0] = sacc[1] = sacc[2] = sacc[3] = zero;
    #pragma unroll
    for (int n = 0; n < 4; n++) {
      const long kb = ((long)(b * 64 + n * 16 + l15)) * 3072 + 1024 + h * 64;
      s16x8 b0 = *(const s16x8*)(qkv + kb + l4 * 8);
      s16x8 b1 = *(const s16x8*)(qkv + kb + 32 + l4 * 8);
      sacc[n] = mfma16(aqs[w][0], b0, sacc[n]);
      sacc[n] = mfma16(aqs[w][1], b1, sacc[n]);
    }
    // qr (+Dh) for own nj set over all t; lane holds 4 consecutive r at fixed t
    const short* rkh = relkb + (long)h * 240 * 64;
    #pragma unroll
    for (int g = 0; g < 4; g++) {
      const int nj = w + g * 4;
      if (nj < 15) {
        const int rr = nj * 16 + l15;
        s16x8 r0 = *(const s16x8*)(rkh + rr * 64 + l4 * 8);
        s16x8 r1 = *(const s16x8*)(rkh + rr * 64 + 32 + l4 * 8);
        const f32x4 dv4 = *(const f32x4*)&Dh[h * 240 + nj * 16 + l4 * 4];
        #pragma unroll
        for (int tb = 0; tb < 4; tb++) {
          f32x4 t0 = mfma16(r1, aqs[tb][1], mfma16(r0, aqs[tb][0], zero));
          const int t = tb * 16 + l15;
          s16x4 q4;
          #pragma unroll
          for (int j = 0; j < 4; j++) q4[j] = f2bf(t0[j] + dv4[j]);
          *(s16x4*)(qrs + t * 512 + ((nj * 32 + l4 * 8) ^ ((t & 7) << 4))) = q4;
        }
      }
    }
  } else {
    // v^T staging (256 threads of waves 4-7 cover 64 rows x 4 col-chunks)
    const int tid2 = tid - 256;
    const int tv = tid2 >> 2, c0 = (tid2 & 3) * 16;
    const long g = ((long)(b * 64 + tv)) * 3072 + 2048 + h * 64 + c0;
    s16x8 v0 = *(const s16x8*)(qkv + g);
    s16x8 v1 = *(const s16x8*)(qkv + g + 8);
    #pragma unroll
    for (int i = 0; i < 8; i++) {
      const int d = c0 + i;
      *(short*)(vts + d * 128 + ((tv * 2) ^ ((d & 7) << 4))) = v0[i];
    }
    #pragma unroll
    for (int i = 0; i < 8; i++) {
      const int d = c0 + 8 + i;
      *(short*)(vts + d * 128 + ((tv * 2) ^ ((d & 7) << 4))) = v1[i];
    }
    // k fragments for all 4 s-tiles
    s16x8 aks[4][2];
    #pragma unroll
    for (int sb = 0; sb < 4; sb++) {
      const long kb = ((long)(b * 64 + sb * 16 + l15)) * 3072 + 1024 + h * 64;
      aks[sb][0] = *(const s16x8*)(qkv + kb + l4 * 8);
      aks[sb][1] = *(const s16x8*)(qkv + kb + 32 + l4 * 8);
    }
    // kr for own nj set over all s
    const int wl = w - 4;
    const short* rqh = relqb + (long)h * 240 * 64;
    #pragma unroll
    for (int g4 = 0; g4 < 4; g4++) {
      const int nj = wl + g4 * 4;
      if (nj < 15) {
        const int rr = nj * 16 + l15;
        s16x8 r0 = *(const s16x8*)(rqh + rr * 64 + l4 * 8);
        s16x8 r1 = *(const s16x8*)(rqh + rr * 64 + 32 + l4 * 8);
        #pragma unroll
        for (int sb = 0; sb < 4; sb++) {
          f32x4 t1 = mfma16(r1, aks[sb][1], mfma16(r0, aks[sb][0], zero));
          const int s = sb * 16 + l15;
          s16x4 k4;
          #pragma unroll
          for (int j = 0; j < 4; j++) k4[j] = f2bf(t1[j]);
          *(s16x4*)(krs + s * 512 + ((nj * 32 + l4 * 8) ^ ((s & 7) << 4))) = k4;
        }
      }
    }
  }
  __syncthreads();   // barrier 1: qr/kr/vts visible

  // ---- PV operand prefetch (ALL waves): 16 relvT fragments into regs ----
  const int tc = w & 3, mb = (w >> 2) * 2;
  const short* rvh = relvT + (long)h * 16384;
  s16x8 rv0[8], rv1[8];
  #pragma unroll
  for (int kk = 0; kk < 8; kk++) {
    rv0[kk] = *(const s16x8*)(rvh + ((mb + 0) * 16 + l15) * 256 + kk * 32 + l4 * 8);
    rv1[kk] = *(const s16x8*)(rvh + ((mb + 1) * 16 + l15) * 256 + kk * 32 + l4 * 8);
  }

  if (w < 4) {
    // gather (r = r0 - j within j-span) + logits (exp2 domain) + softmax
    const float scale2 = 0.18033688f;   // 0.125 * log2(e)
    const int tx0 = (l4 & 1) * 4;
    const int ty = w * 2 + (l4 >> 1);
    const int tbase = w * 16 + l4 * 4;
    #pragma unroll
    for (int n = 0; n < 4; n++) {
      const int s = n * 16 + l15;
      const int sx = s & 7, sy = s >> 3;
      const int r0 = (7 - tx0 + sx) + 15 * (7 - ty + sy);
      const int kga = s * 512;
      const int ksw = (s & 7) << 4;
      #pragma unroll
      for (int j = 0; j < 4; j++) {
        const int t = tbase + j;
        const int r = r0 - j;
        const float qg = bf2f(*(const short*)(qrs + t * 512 + ((r * 2) ^ ((t & 7) << 4))));
        const float kg = bf2f(*(const short*)(krs + kga + ((r * 2) ^ ksw)));
        sacc[n][j] = (sacc[n][j] + qg + kg) * scale2;
      }
    }
    #pragma unroll
    for (int j = 0; j < 4; j++) {
      float m = fmaxf(fmaxf(sacc[0][j], sacc[1][j]), fmaxf(sacc[2][j], sacc[3][j]));
      m = fmaxf(m, __shfl_xor(m, 1));
      m = fmaxf(m, __shfl_xor(m, 2));
      m = fmaxf(m, __shfl_xor(m, 4));
      m = fmaxf(m, __shfl_xor(m, 8));
      float sum = 0.f;
      #pragma unroll
      for (int n = 0; n < 4; n++) { att[n][j] = exp2f(sacc[n][j] - m); sum += att[n][j]; }
      sum += __shfl_xor(sum, 1);
      sum += __shfl_xor(sum, 2);
      sum += __shfl_xor(sum, 4);
      sum += __shfl_xor(sum, 8);
      const float inv = 1.f / sum;
      #pragma unroll
      for (int n = 0; n < 4; n++) att[n][j] *= inv;
    }
  }
  __syncthreads();   // barrier 2: qr/kr reads done -> region reusable as Pb

  char* Pb = region;
  if (w < 4) {
    // zero wave-own P rows, scatter P + attn (swizzled, collision-free)
    s16x8 z = {0, 0, 0, 0, 0, 0, 0, 0};
    #pragma unroll
    for (int i = 0; i < 8; i++) {
      const int c = lane + 64 * i;
      *(s16x8*)(Pb + (w * 16 + (c >> 5)) * 640 + (c & 31) * 16) = z;
    }
    const int tx0 = (l4 & 1) * 4;
    const int ty = w * 2 + (l4 >> 1);
    const int tbase = w * 16 + l4 * 4;
    #pragma unroll
    for (int n = 0; n < 4; n++) {
      const int s = n * 16 + l15;
      const int sx = s & 7, sy = s >> 3;
      const int r0 = (7 - tx0 + sx) + 15 * (7 - ty + sy);
      #pragma unroll
      for (int j = 0; j < 4; j++) {
        const int t = tbase + j;
        const int r = r0 - j;
        const int sw = (t & 7) << 4;
        const short a = f2bf(att[n][j]);
        *(short*)(Pb + t * 640 + ((r * 2) ^ sw)) = a;
        *(short*)(Pb + t * 640 + 512 + ((s * 2) ^ sw)) = a;
      }
    }
  }
  __syncthreads();   // barrier 3: Pb complete

  // PV: wave w owns t-column tc and d-blocks mb, mb+1 (relvT operands in regs)
  const int rowp = tc * 16 + l15, px = (rowp & 7) << 4;
  f32x4 oacc0 = zero, oacc1 = zero;
  PRIO1;
  #pragma unroll
  for (int kk = 0; kk < 8; kk++) {
    s16x8 pa = *(const s16x8*)(Pb + rowp * 640 + ((kk * 64 + l4 * 16) ^ px));
    oacc0 = mfma16(rv0[kk], pa, oacc0);
    oacc1 = mfma16(rv1[kk], pa, oacc1);
  }
  #pragma unroll
  for (int ks = 0; ks < 2; ks++) {
    s16x8 pa = *(const s16x8*)(Pb + rowp * 640 + 512 + ((ks * 64 + l4 * 16) ^ px));
    const int d0 = (mb + 0) * 16 + l15;
    const int d1 = (mb + 1) * 16 + l15;
    s16x8 bv0 = *(const s16x8*)(vts + d0 * 128 + ((ks * 64 + l4 * 16) ^ ((d0 & 7) << 4)));
    s16x8 bv1 = *(const s16x8*)(vts + d1 * 128 + ((ks * 64 + l4 * 16) ^ ((d1 & 7) << 4)));
    oacc0 = mfma16(bv0, pa, oacc0);
    oacc1 = mfma16(bv1, pa, oacc1);
  }
  PRIO0;
  // out[d][t]: packed 8-B stores
  const long obase = ((long)(b * 64 + rowp)) * 1024 + h * 64 + l4 * 4;
  {
    s16x4 o0, o1;
    #pragma unroll
    for (int j = 0; j < 4; j++) { o0[j] = f2bf(oacc0[j]); o1[j] = f2bf(oacc1[j]); }
    *(s16x4*)(aout + obase + (mb + 0) * 16) = o0;
    *(s16x4*)(aout + obase + (mb + 1) * 16) = o1;
  }
}

extern "C" void kernel_launch(void* const* d_in, const int* in_sizes, int n_in,
                              void* d_out, int out_size, void* d_ws, size_t ws_size,
                              hipStream_t stream) {
  const float* x     = (const float*)d_in[0];
  const float* Wq_w  = (const float*)d_in[1];
  const float* Wq_b  = (const float*)d_in[2];
  const float* Wk_w  = (const float*)d_in[3];
  const float* Wk_b  = (const float*)d_in[4];
  const float* Wv_w  = (const float*)d_in[5];
  const float* Wv_b  = (const float*)d_in[6];
  const float* Wo_w  = (const float*)d_in[7];
  const float* Wo_b  = (const float*)d_in[8];
  const float* rel_q = (const float*)d_in[9];
  const float* rel_k = (const float*)d_in[10];
  const float* rel_v = (const float*)d_in[11];
  float* out = (float*)d_out;

  char* ws = (char*)d_ws;
  short* x_bf   = (short*)(ws);                   // 134,217,728 (reused as aout)
  short* qkv_bf = (short*)(ws + 134217728L);      // 402,653,184
  short* wq_bf  = (short*)(ws + 536870912L);      // wq|wk|wv contiguous
  short* wo_bf  = (short*)(ws + 543162368L);
  float* biascat= (float*)(ws + 545259520L);
  short* relqb  = (short*)(ws + 545271808L);
  short* relkb  = (short*)(ws + 545763328L);
  short* relvT  = (short*)(ws + 546254848L);
  float* Dh     = (float*)(ws + 546779136L);
  short* aout   = x_bf;

  cvt_bf16_kernel<<<65536, 256, 0, stream>>>(x, x_bf, 67108864L);
  cvt_bf16_kernel<<<1024, 256, 0, stream>>>(Wq_w, wq_bf, 1048576L);
  cvt_bf16_kernel<<<1024, 256, 0, stream>>>(Wk_w, (short*)(ws + 538968064L), 1048576L);
  cvt_bf16_kernel<<<1024, 256, 0, stream>>>(Wv_w, (short*)(ws + 541065216L), 1048576L);
  cvt_bf16_kernel<<<1024, 256, 0, stream>>>(Wo_w, wo_bf, 1048576L);
  bias_cat_kernel<<<12, 256, 0, stream>>>(Wq_b, Wk_b, Wv_b, biascat);
  prep_rel_kernel<<<3840, 64, 0, stream>>>(rel_q, rel_k, rel_v, relqb, relkb, relvT, Dh);

  gemm256_kernel<1><<<3072, 512, 0, stream>>>(x_bf, wq_bf, biascat, (void*)qkv_bf,
                                              3072, 1024, 1024);
  attn_kernel<<<16384, 512, 0, stream>>>(qkv_bf, relqb, relkb, Dh, relvT, aout);
  gemm256_kernel<0><<<1024, 512, 0, stream>>>(aout, wo_bf, Wo_b, (void*)out,
                                              1024, 1024, 1024);
}